// Round 3
// baseline (569.602 us; speedup 1.0000x reference)
//
#include <hip/hip_runtime.h>

#define N_ATOMS 20000
#define N_EDGES 80000
#define ATOM_DIM 29
#define BOND_DIM 11
#define UNITS 64
#define STEPS 4
#define GCOLS ((BOND_DIM+1)*UNITS)   // 768: 11 bond-weighted slices + 1 plain-sum slice

__global__ void init_h(const float* __restrict__ atom, float* __restrict__ h) {
    int idx = blockIdx.x*256 + threadIdx.x;
    if (idx >= N_ATOMS*UNITS) return;
    int a = idx / UNITS, i = idx % UNITS;
    h[idx] = (i < ATOM_DIM) ? atom[a*ATOM_DIM + i] : 0.f;
}

// EKT2[k][i], k=b*64+j: b<11 -> ek[b, i*64+j]; b==11 -> eb[i*64+j]
__global__ void build_ekt2(const float* __restrict__ ek, const float* __restrict__ eb,
                           float* __restrict__ ekt2) {
    int idx = blockIdx.x*256 + threadIdx.x;
    if (idx >= GCOLS*UNITS) return;
    int k = idx >> 6, i = idx & 63;
    int b = k >> 6, j = k & 63;
    ekt2[idx] = (b < BOND_DIM) ? ek[b*(UNITS*UNITS) + i*UNITS + j] : eb[i*UNITS + j];
}

// W2[j][c], j in [0,128), c = comp*64+i, comp: 0=zsum 1=rsum 2=xh 3=rh
__global__ void build_w2(const float* __restrict__ gk, const float* __restrict__ grk,
                         const float* __restrict__ gb, float* __restrict__ W2,
                         float* __restrict__ bias2) {
    int idx = blockIdx.x*256 + threadIdx.x;
    if (idx < 256) {
        int comp = idx >> 6, i = idx & 63;
        float b;
        if (comp == 0)      b = gb[i]       + gb[192 + i];
        else if (comp == 1) b = gb[64 + i]  + gb[192 + 64 + i];
        else if (comp == 2) b = gb[128 + i];
        else                b = gb[192 + 128 + i];
        bias2[idx] = b;
    }
    if (idx >= 128*256) return;
    int j = idx >> 8, c = idx & 255;
    int comp = c >> 6, i = c & 63;
    float v;
    if (j < 64) {
        v = (comp == 0) ? gk[j*192 + i]
          : (comp == 1) ? gk[j*192 + 64 + i]
          : (comp == 2) ? gk[j*192 + 128 + i] : 0.f;
    } else {
        int jj = j - 64;
        v = (comp == 0) ? grk[jj*192 + i]
          : (comp == 1) ? grk[jj*192 + 64 + i]
          : (comp == 3) ? grk[jj*192 + 128 + i] : 0.f;
    }
    W2[idx] = v;
}

// One wave per atom: G[a, b*64+j] = sum_{e: src=a} bond[e,b]*h[dst_e, j]
// (b=11 slice: plain sum). Edges sorted by src -> binary-search range, no atomics.
__global__ __launch_bounds__(256) void edge_g(const int* __restrict__ pair,
    const float* __restrict__ bond, const float* __restrict__ h,
    float* __restrict__ G) {
  int wid  = threadIdx.x >> 6;
  int lane = threadIdx.x & 63;
  int a = blockIdx.x*4 + wid;
  if (a >= N_ATOMS) return;

  // lower_bound(a) and lower_bound(a+1) in pair[:,0] (uniform across wave)
  int lo = 0, hi = N_EDGES;
  while (lo < hi) { int mid = (lo+hi)>>1; if (pair[2*mid] < a) lo = mid+1; else hi = mid; }
  int start = lo;
  hi = N_EDGES;
  while (lo < hi) { int mid = (lo+hi)>>1; if (pair[2*mid] < a+1) lo = mid+1; else hi = mid; }
  int end = lo;

  float g[BOND_DIM+1];
  #pragma unroll
  for (int b=0;b<=BOND_DIM;b++) g[b] = 0.f;

  for (int e = start; e < end; e++) {
    int dst = pair[2*e+1];
    float hv = h[(size_t)dst*UNITS + lane];
    g[BOND_DIM] += hv;
    #pragma unroll
    for (int b=0;b<BOND_DIM;b++) g[b] += bond[e*BOND_DIM + b] * hv;
  }
  #pragma unroll
  for (int b=0;b<=BOND_DIM;b++)
    G[(size_t)a*GCOLS + b*UNITS + lane] = g[b];
}

// msg = G(20000x768) @ EKT2(768x64). Block 256, 64 atoms.
// tx=tid&15 -> cols tx*4..+3 ; ty=tid>>4 -> rows ty*4..+3. acc[4][4].
__global__ __launch_bounds__(256) void msg_gemm(const float* __restrict__ G,
    const float* __restrict__ ekt2, float* __restrict__ msg) {
  __shared__ float Xs[64][36];
  __shared__ float Ws[32][68];
  int a0 = blockIdx.x * 64;
  int tid = threadIdx.x;
  int tx = tid & 15, ty = tid >> 4;
  float acc[4][4];
  #pragma unroll
  for (int i=0;i<4;i++) for (int q=0;q<4;q++) acc[i][q]=0.f;

  for (int kt = 0; kt < GCOLS/32; kt++) {
    {
      int r = tid >> 2, kk = (tid & 3) * 8;
      int ar = a0 + r; if (ar >= N_ATOMS) ar = N_ATOMS - 1;
      const float* src = &G[(size_t)ar*GCOLS + kt*32 + kk];
      *(float4*)&Xs[r][kk]     = *(const float4*)&src[0];
      *(float4*)&Xs[r][kk + 4] = *(const float4*)&src[4];
    }
    {
      int jr = tid >> 3, c0 = (tid & 7) * 8;
      const float* src = &ekt2[(size_t)(kt*32 + jr)*UNITS + c0];
      *(float4*)&Ws[jr][c0]     = *(const float4*)&src[0];
      *(float4*)&Ws[jr][c0 + 4] = *(const float4*)&src[4];
    }
    __syncthreads();
    #pragma unroll
    for (int k = 0; k < 32; k++) {
      float4 w = *(const float4*)&Ws[k][tx*4];
      float xv[4];
      #pragma unroll
      for (int i=0;i<4;i++) xv[i] = Xs[ty*4 + i][k];
      #pragma unroll
      for (int i=0;i<4;i++) {
        acc[i][0] += xv[i]*w.x; acc[i][1] += xv[i]*w.y;
        acc[i][2] += xv[i]*w.z; acc[i][3] += xv[i]*w.w;
      }
    }
    __syncthreads();
  }
  #pragma unroll
  for (int i=0;i<4;i++) {
    int a = a0 + ty*4 + i;
    if (a < N_ATOMS)
      *(float4*)&msg[(size_t)a*UNITS + tx*4] =
          make_float4(acc[i][0], acc[i][1], acc[i][2], acc[i][3]);
  }
}

// Fused GRU: [msg|h](20000x128) @ W2(128x256) + bias2 -> gates -> h update.
__global__ __launch_bounds__(256) void gru_fused(const float* __restrict__ msg,
    float* __restrict__ h, const float* __restrict__ W2,
    const float* __restrict__ bias2) {
  __shared__ float Xs[32][36];
  __shared__ float Ws[32][256];
  int a0 = blockIdx.x * 32;
  int tid = threadIdx.x;
  int tx = tid & 31, ty = tid >> 5;
  float acc[4][4][2];
  #pragma unroll
  for (int i=0;i<4;i++) for (int q=0;q<4;q++) { acc[i][q][0]=0.f; acc[i][q][1]=0.f; }

  for (int kt = 0; kt < 4; kt++) {
    {
      int r = tid >> 3, kk = (tid & 7) * 4;
      const float* xsrc = (kt < 2) ? msg : h;
      int koff = (kt < 2) ? kt*32 : (kt-2)*32;
      *(float4*)&Xs[r][kk] = *(const float4*)&xsrc[(size_t)(a0 + r)*UNITS + koff + kk];
    }
    {
      int jr = tid >> 3, c0 = (tid & 7) * 32;
      const float* src = &W2[(size_t)(kt*32 + jr)*256 + c0];
      #pragma unroll
      for (int v = 0; v < 8; v++)
        *(float4*)&Ws[jr][c0 + v*4] = *(const float4*)&src[v*4];
    }
    __syncthreads();
    #pragma unroll
    for (int k = 0; k < 32; k++) {
      float xv[4];
      #pragma unroll
      for (int i=0;i<4;i++) xv[i] = Xs[ty*4 + i][k];
      #pragma unroll
      for (int q=0;q<4;q++) {
        float2 w = *(const float2*)&Ws[k][q*64 + tx*2];
        #pragma unroll
        for (int i=0;i<4;i++) { acc[i][q][0] += xv[i]*w.x; acc[i][q][1] += xv[i]*w.y; }
      }
    }
    __syncthreads();
  }

  float2 bz  = *(const float2*)&bias2[tx*2];
  float2 br  = *(const float2*)&bias2[64  + tx*2];
  float2 bh  = *(const float2*)&bias2[128 + tx*2];
  float2 brh = *(const float2*)&bias2[192 + tx*2];
  #pragma unroll
  for (int i=0;i<4;i++) {
    int a = a0 + ty*4 + i;
    float2 hold = *(const float2*)&h[(size_t)a*UNITS + tx*2];
    float hn[2];
    #pragma unroll
    for (int u=0; u<2; u++) {
      float holdv = u ? hold.y : hold.x;
      float zs = acc[i][0][u] + (u ? bz.y  : bz.x);
      float rs = acc[i][1][u] + (u ? br.y  : br.x);
      float xh = acc[i][2][u] + (u ? bh.y  : bh.x);
      float rh = acc[i][3][u] + (u ? brh.y : brh.x);
      float z = 1.f/(1.f + __expf(-zs));
      float r = 1.f/(1.f + __expf(-rs));
      float hh = tanhf(xh + r*rh);
      hn[u] = z*holdv + (1.f - z)*hh;
    }
    *(float2*)&h[(size_t)a*UNITS + tx*2] = make_float2(hn[0], hn[1]);
  }
}

extern "C" void kernel_launch(void* const* d_in, const int* in_sizes, int n_in,
                              void* d_out, int out_size, void* d_ws, size_t ws_size,
                              hipStream_t stream) {
  const float* atom  = (const float*)d_in[0];
  const float* bond  = (const float*)d_in[1];
  const int*   pair  = (const int*)d_in[2];
  const float* ek    = (const float*)d_in[3];
  const float* eb    = (const float*)d_in[4];
  const float* gk    = (const float*)d_in[5];
  const float* grk   = (const float*)d_in[6];
  const float* gbias = (const float*)d_in[7];

  float* h     = (float*)d_out;                      // 20000x64 fp32
  float* ws    = (float*)d_ws;
  float* ekt2  = ws;                                 // 768*64
  float* W2    = ekt2 + (size_t)GCOLS*UNITS;         // 128*256
  float* bias2 = W2 + 128*256;                       // 256
  float* G     = bias2 + 256;                        // 20000*768
  float* msg   = G + (size_t)N_ATOMS*GCOLS;          // 20000*64

  init_h<<<(N_ATOMS*UNITS+255)/256, 256, 0, stream>>>(atom, h);
  build_ekt2<<<(GCOLS*UNITS+255)/256, 256, 0, stream>>>(ek, eb, ekt2);
  build_w2<<<(128*256+255)/256, 256, 0, stream>>>(gk, grk, gbias, W2, bias2);

  for (int s=0; s<STEPS; s++) {
    edge_g<<<(N_ATOMS+3)/4, 256, 0, stream>>>(pair, bond, h, G);
    msg_gemm<<<(N_ATOMS+63)/64, 256, 0, stream>>>(G, ekt2, msg);
    gru_fused<<<N_ATOMS/32, 256, 0, stream>>>(msg, h, W2, bias2);
  }
}

// Round 4
// 354.769 us; speedup vs baseline: 1.6056x; 1.6056x over previous
//
#include <hip/hip_runtime.h>

#define N_ATOMS 20000
#define N_EDGES 80000
#define ATOM_DIM 29
#define BOND_DIM 11
#define UNITS 64
#define STEPS 4
#define GCOLS ((BOND_DIM+1)*UNITS)   // 768

typedef _Float16 f16;
typedef __attribute__((ext_vector_type(8))) _Float16 f16x8;
typedef __attribute__((ext_vector_type(4))) float f32x4;

__global__ void init_h(const float* __restrict__ atom, float* __restrict__ h) {
    int idx = blockIdx.x*256 + threadIdx.x;
    if (idx >= N_ATOMS*UNITS) return;
    int a = idx / UNITS, i = idx % UNITS;
    h[idx] = (i < ATOM_DIM) ? atom[a*ATOM_DIM + i] : 0.f;
}

// row_ptr[a] = first edge index with src >= a (edges sorted by src)
__global__ void build_rowptr(const int* __restrict__ pair, int* __restrict__ row_ptr) {
    int e = blockIdx.x*256 + threadIdx.x;
    if (e >= N_EDGES) return;
    int s = pair[2*e];
    if (e == 0) for (int a = 0; a <= s; a++) row_ptr[a] = 0;
    int snext = (e == N_EDGES-1) ? N_ATOMS : pair[2*(e+1)];
    for (int a = s+1; a <= snext; a++) row_ptr[a] = e+1;
}

// EKT2T[i][k], k=b*64+j: b<11 -> ek[b, i*64+j]; b==11 -> eb[i*64+j]  (f16)
__global__ void build_ekt2t(const float* __restrict__ ek, const float* __restrict__ eb,
                            f16* __restrict__ ekt2t) {
    int idx = blockIdx.x*256 + threadIdx.x;
    if (idx >= UNITS*GCOLS) return;
    int i = idx / GCOLS, k = idx % GCOLS;
    int b = k >> 6, j = k & 63;
    float v = (b < BOND_DIM) ? ek[b*(UNITS*UNITS) + i*UNITS + j] : eb[i*UNITS + j];
    ekt2t[idx] = (f16)v;
}

// W2[j][c], j in [0,128), c = comp*64+i, comp: 0=zsum 1=rsum 2=xh 3=rh
__global__ void build_w2(const float* __restrict__ gk, const float* __restrict__ grk,
                         const float* __restrict__ gb, float* __restrict__ W2,
                         float* __restrict__ bias2) {
    int idx = blockIdx.x*256 + threadIdx.x;
    if (idx < 256) {
        int comp = idx >> 6, i = idx & 63;
        float b;
        if (comp == 0)      b = gb[i]       + gb[192 + i];
        else if (comp == 1) b = gb[64 + i]  + gb[192 + 64 + i];
        else if (comp == 2) b = gb[128 + i];
        else                b = gb[192 + 128 + i];
        bias2[idx] = b;
    }
    if (idx >= 128*256) return;
    int j = idx >> 8, c = idx & 255;
    int comp = c >> 6, i = c & 63;
    float v;
    if (j < 64) {
        v = (comp == 0) ? gk[j*192 + i]
          : (comp == 1) ? gk[j*192 + 64 + i]
          : (comp == 2) ? gk[j*192 + 128 + i] : 0.f;
    } else {
        int jj = j - 64;
        v = (comp == 0) ? grk[jj*192 + i]
          : (comp == 1) ? grk[jj*192 + 64 + i]
          : (comp == 3) ? grk[jj*192 + 128 + i] : 0.f;
    }
    W2[idx] = v;
}

// One wave per atom; no binary search (row_ptr), G written as f16.
__global__ __launch_bounds__(256) void edge_g(const int* __restrict__ pair,
    const int* __restrict__ row_ptr, const float* __restrict__ bond,
    const float* __restrict__ h, f16* __restrict__ G) {
  int wid  = threadIdx.x >> 6;
  int lane = threadIdx.x & 63;
  int a = blockIdx.x*4 + wid;
  if (a >= N_ATOMS) return;
  int start = row_ptr[a], end = row_ptr[a+1];

  float g[BOND_DIM+1];
  #pragma unroll
  for (int b=0;b<=BOND_DIM;b++) g[b] = 0.f;

  for (int e = start; e < end; e++) {
    int dst = pair[2*e+1];
    float hv = h[(size_t)dst*UNITS + lane];
    g[BOND_DIM] += hv;
    #pragma unroll
    for (int b=0;b<BOND_DIM;b++) g[b] += bond[e*BOND_DIM + b] * hv;
  }
  #pragma unroll
  for (int b=0;b<=BOND_DIM;b++)
    G[(size_t)a*GCOLS + b*UNITS + lane] = (f16)g[b];
}

// msg(20000x64) = G(20000x768,f16) @ EKT2(768x64,f16)  via MFMA 16x16x32 f16.
// Block 256 (4 waves), 32 atoms. wave(wr=wid>>1 rows, wc2=wid&1 col-half).
__global__ __launch_bounds__(256) void msg_gemm_mfma(const f16* __restrict__ G,
    const f16* __restrict__ ekt2t, float* __restrict__ msg) {
  __shared__ f16 As[32][40];   // 32 rows x 32 k (pad 40)
  __shared__ f16 Wt[64][40];   // 64 cols x 32 k (pad 40)
  int a0 = blockIdx.x * 32;
  int tid = threadIdx.x;
  int lane = tid & 63, wid = tid >> 6;
  int wr = wid >> 1, wc2 = wid & 1;

  f32x4 acc[2];
  acc[0] = (f32x4){0.f,0.f,0.f,0.f};
  acc[1] = (f32x4){0.f,0.f,0.f,0.f};

  for (int kt = 0; kt < GCOLS/32; kt++) {
    if (tid < 128) {
      int r = tid >> 2, k0 = (tid & 3) * 8;
      *(f16x8*)&As[r][k0] = *(const f16x8*)&G[(size_t)(a0 + r)*GCOLS + kt*32 + k0];
    }
    {
      int c = tid >> 2, k0 = (tid & 3) * 8;
      *(f16x8*)&Wt[c][k0] = *(const f16x8*)&ekt2t[(size_t)c*GCOLS + kt*32 + k0];
    }
    __syncthreads();
    f16x8 af = *(const f16x8*)&As[wr*16 + (lane & 15)][(lane >> 4)*8];
    #pragma unroll
    for (int n = 0; n < 2; n++) {
      f16x8 bf = *(const f16x8*)&Wt[wc2*32 + n*16 + (lane & 15)][(lane >> 4)*8];
      acc[n] = __builtin_amdgcn_mfma_f32_16x16x32_f16(af, bf, acc[n], 0, 0, 0);
    }
    __syncthreads();
  }
  #pragma unroll
  for (int n = 0; n < 2; n++) {
    int col = wc2*32 + n*16 + (lane & 15);
    int r0  = wr*16 + (lane >> 4)*4;
    #pragma unroll
    for (int r = 0; r < 4; r++)
      msg[(size_t)(a0 + r0 + r)*UNITS + col] = acc[n][r];
  }
}

// Fused GRU: [msg|h](20000x128) @ W2(128x256) + bias2 -> gates -> h update. (fp32)
__global__ __launch_bounds__(256) void gru_fused(const float* __restrict__ msg,
    float* __restrict__ h, const float* __restrict__ W2,
    const float* __restrict__ bias2) {
  __shared__ float Xs[32][36];
  __shared__ float Ws[32][256];
  int a0 = blockIdx.x * 32;
  int tid = threadIdx.x;
  int tx = tid & 31, ty = tid >> 5;
  float acc[4][4][2];
  #pragma unroll
  for (int i=0;i<4;i++) for (int q=0;q<4;q++) { acc[i][q][0]=0.f; acc[i][q][1]=0.f; }

  for (int kt = 0; kt < 4; kt++) {
    {
      int r = tid >> 3, kk = (tid & 7) * 4;
      const float* xsrc = (kt < 2) ? msg : h;
      int koff = (kt < 2) ? kt*32 : (kt-2)*32;
      *(float4*)&Xs[r][kk] = *(const float4*)&xsrc[(size_t)(a0 + r)*UNITS + koff + kk];
    }
    {
      int jr = tid >> 3, c0 = (tid & 7) * 32;
      const float* src = &W2[(size_t)(kt*32 + jr)*256 + c0];
      #pragma unroll
      for (int v = 0; v < 8; v++)
        *(float4*)&Ws[jr][c0 + v*4] = *(const float4*)&src[v*4];
    }
    __syncthreads();
    #pragma unroll
    for (int k = 0; k < 32; k++) {
      float xv[4];
      #pragma unroll
      for (int i=0;i<4;i++) xv[i] = Xs[ty*4 + i][k];
      #pragma unroll
      for (int q=0;q<4;q++) {
        float2 w = *(const float2*)&Ws[k][q*64 + tx*2];
        #pragma unroll
        for (int i=0;i<4;i++) { acc[i][q][0] += xv[i]*w.x; acc[i][q][1] += xv[i]*w.y; }
      }
    }
    __syncthreads();
  }

  float2 bz  = *(const float2*)&bias2[tx*2];
  float2 br  = *(const float2*)&bias2[64  + tx*2];
  float2 bh  = *(const float2*)&bias2[128 + tx*2];
  float2 brh = *(const float2*)&bias2[192 + tx*2];
  #pragma unroll
  for (int i=0;i<4;i++) {
    int a = a0 + ty*4 + i;
    float2 hold = *(const float2*)&h[(size_t)a*UNITS + tx*2];
    float hn[2];
    #pragma unroll
    for (int u=0; u<2; u++) {
      float holdv = u ? hold.y : hold.x;
      float zs = acc[i][0][u] + (u ? bz.y  : bz.x);
      float rs = acc[i][1][u] + (u ? br.y  : br.x);
      float xh = acc[i][2][u] + (u ? bh.y  : bh.x);
      float rh = acc[i][3][u] + (u ? brh.y : brh.x);
      float z = 1.f/(1.f + __expf(-zs));
      float r = 1.f/(1.f + __expf(-rs));
      float hh = tanhf(xh + r*rh);
      hn[u] = z*holdv + (1.f - z)*hh;
    }
    *(float2*)&h[(size_t)a*UNITS + tx*2] = make_float2(hn[0], hn[1]);
  }
}

extern "C" void kernel_launch(void* const* d_in, const int* in_sizes, int n_in,
                              void* d_out, int out_size, void* d_ws, size_t ws_size,
                              hipStream_t stream) {
  const float* atom  = (const float*)d_in[0];
  const float* bond  = (const float*)d_in[1];
  const int*   pair  = (const int*)d_in[2];
  const float* ek    = (const float*)d_in[3];
  const float* eb    = (const float*)d_in[4];
  const float* gk    = (const float*)d_in[5];
  const float* grk   = (const float*)d_in[6];
  const float* gbias = (const float*)d_in[7];

  float* h = (float*)d_out;                          // 20000x64 fp32

  char* w = (char*)d_ws;
  int*   row_ptr = (int*)w;        w += (size_t)20004*4;
  f16*   ekt2t   = (f16*)w;        w += (size_t)UNITS*GCOLS*2;
  float* W2      = (float*)w;      w += (size_t)128*256*4;
  float* bias2   = (float*)w;      w += (size_t)256*4;
  f16*   G       = (f16*)w;        w += (size_t)N_ATOMS*GCOLS*2;
  float* msg     = (float*)w;

  init_h<<<(N_ATOMS*UNITS+255)/256, 256, 0, stream>>>(atom, h);
  build_rowptr<<<(N_EDGES+255)/256, 256, 0, stream>>>(pair, row_ptr);
  build_ekt2t<<<(UNITS*GCOLS+255)/256, 256, 0, stream>>>(ek, eb, ekt2t);
  build_w2<<<(128*256+255)/256, 256, 0, stream>>>(gk, grk, gbias, W2, bias2);

  for (int s=0; s<STEPS; s++) {
    edge_g<<<(N_ATOMS+3)/4, 256, 0, stream>>>(pair, row_ptr, bond, h, G);
    msg_gemm_mfma<<<N_ATOMS/32, 256, 0, stream>>>(G, ekt2t, msg);
    gru_fused<<<N_ATOMS/32, 256, 0, stream>>>(msg, h, W2, bias2);
  }
}

// Round 5
// 335.917 us; speedup vs baseline: 1.6957x; 1.0561x over previous
//
#include <hip/hip_runtime.h>

#define N_ATOMS 20000
#define N_EDGES 80000
#define ATOM_DIM 29
#define BOND_DIM 11
#define UNITS 64
#define STEPS 4
#define GCOLS 768      // 12*64 (11 bond slices + 1 plain-sum slice)
#define KTOT  832      // 768 (G) + 64 (h)
#define NCOLS 256      // 4 comps x 64 units

typedef _Float16 f16;
typedef __attribute__((ext_vector_type(8))) _Float16 f16x8;
typedef __attribute__((ext_vector_type(4))) float f32x4;

__global__ void init_h(const float* __restrict__ atom, float* __restrict__ h,
                       f16* __restrict__ h16) {
    int idx = blockIdx.x*256 + threadIdx.x;
    if (idx >= N_ATOMS*UNITS) return;
    int a = idx >> 6, i = idx & 63;
    float v = (i < ATOM_DIM) ? atom[a*ATOM_DIM + i] : 0.f;
    h[idx] = v;
    h16[idx] = (f16)v;
}

// row_ptr[a] = first edge index with src >= a (edges sorted by src)
__global__ void build_rowptr(const int* __restrict__ pair, int* __restrict__ row_ptr) {
    int e = blockIdx.x*256 + threadIdx.x;
    if (e >= N_EDGES) return;
    int s = pair[2*e];
    if (e == 0) for (int a = 0; a <= s; a++) row_ptr[a] = 0;
    int snext = (e == N_EDGES-1) ? N_ATOMS : pair[2*(e+1)];
    for (int a = s+1; a <= snext; a++) row_ptr[a] = e+1;
}

// W3T[c][k] (f16, 256 x 832), c = comp*64+i, comp: 0=zsum 1=rsum 2=xh 3=rh.
// k<768 (k=b*64+q): sum_m E[k,m]*W2top[m,c] with E[k,m]=ek[b,m*64+q] (b<11) or eb[m*64+q].
// k>=768 (j=k-768): W2bot[j,c] from grk. Also bias2[c] (f32) from gb.
__global__ void build_w3t(const float* __restrict__ ek, const float* __restrict__ eb,
                          const float* __restrict__ gk, const float* __restrict__ grk,
                          const float* __restrict__ gb, f16* __restrict__ W3T,
                          float* __restrict__ bias2) {
    int idx = blockIdx.x*256 + threadIdx.x;
    if (idx >= NCOLS*KTOT) return;
    int c = idx & 255, k = idx >> 8;
    int comp = c >> 6, i = c & 63;
    if (k == 0) {
        float b;
        if (comp == 0)      b = gb[i]       + gb[192 + i];
        else if (comp == 1) b = gb[64 + i]  + gb[192 + 64 + i];
        else if (comp == 2) b = gb[128 + i];
        else                b = gb[192 + 128 + i];
        bias2[c] = b;
    }
    float val = 0.f;
    if (k < GCOLS) {
        if (comp != 3) {
            int b = k >> 6, q = k & 63;
            const float* E = (b < BOND_DIM) ? (ek + (size_t)b*4096 + q) : (eb + q);
            const float* T = gk + comp*64 + i;
            #pragma unroll 8
            for (int m = 0; m < 64; m++) val += E[m*64] * T[m*192];
        }
    } else {
        int j = k - GCOLS;
        if (comp == 0)      val = grk[j*192 + i];
        else if (comp == 1) val = grk[j*192 + 64 + i];
        else if (comp == 3) val = grk[j*192 + 128 + i];
    }
    W3T[(size_t)c*KTOT + k] = (f16)val;
}

// One wave per atom: G[a, b*64+j] = sum_{e in a} bond[e,b]*h16[dst_e, j]
// (b=11: plain sum). row_ptr gives the edge range; 2x unrolled for ILP.
__global__ __launch_bounds__(256) void edge_g(const int* __restrict__ pair,
    const int* __restrict__ row_ptr, const float* __restrict__ bond,
    const f16* __restrict__ h16, f16* __restrict__ G) {
  int wid  = threadIdx.x >> 6;
  int lane = threadIdx.x & 63;
  int a = blockIdx.x*4 + wid;
  if (a >= N_ATOMS) return;
  int start = row_ptr[a], end = row_ptr[a+1];

  float g[BOND_DIM+1];
  #pragma unroll
  for (int b=0;b<=BOND_DIM;b++) g[b] = 0.f;

  int e = start;
  for (; e + 1 < end; e += 2) {
    int d0 = pair[2*e+1], d1 = pair[2*e+3];
    float h0 = (float)h16[(size_t)d0*UNITS + lane];
    float h1 = (float)h16[(size_t)d1*UNITS + lane];
    g[BOND_DIM] += h0 + h1;
    #pragma unroll
    for (int b=0;b<BOND_DIM;b++)
      g[b] += bond[e*BOND_DIM + b]*h0 + bond[(e+1)*BOND_DIM + b]*h1;
  }
  if (e < end) {
    int d0 = pair[2*e+1];
    float h0 = (float)h16[(size_t)d0*UNITS + lane];
    g[BOND_DIM] += h0;
    #pragma unroll
    for (int b=0;b<BOND_DIM;b++) g[b] += bond[e*BOND_DIM + b]*h0;
  }
  #pragma unroll
  for (int b=0;b<=BOND_DIM;b++)
    G[(size_t)a*GCOLS + b*UNITS + lane] = (f16)g[b];
}

// gates(20000x256) = [G | h16](20000x832) @ W3T^T + bias2 -> GRU epilogue -> h, h16.
// Block 256 (4 waves), BM=32 atoms, full N=256. Wave w: all 32 rows, i in [w*16,w*16+16),
// all 4 comps: frag cols c = n*64 + w*16 + (lane&15). Lane-local gate math.
__global__ __launch_bounds__(256) void gru2(const f16* __restrict__ G,
    f16* __restrict__ h16, const f16* __restrict__ W3T,
    const float* __restrict__ bias2, float* __restrict__ h) {
  __shared__ f16 As[32][40];    // 32 rows x 32 k
  __shared__ f16 Bt[NCOLS][40]; // 256 cols x 32 k
  int a0 = blockIdx.x * 32;
  int tid = threadIdx.x;
  int lane = tid & 63, w = tid >> 6;
  int lq = lane >> 4, lr = lane & 15;

  f32x4 acc[2][4];
  #pragma unroll
  for (int m=0;m<2;m++)
    #pragma unroll
    for (int n=0;n<4;n++) acc[m][n] = (f32x4){0.f,0.f,0.f,0.f};

  for (int kt = 0; kt < KTOT/32; kt++) {
    if (tid < 128) {
      int r = tid >> 2, k0 = (tid & 3)*8;
      const f16* src = (kt < GCOLS/32)
          ? &G[(size_t)(a0+r)*GCOLS + kt*32 + k0]
          : &h16[(size_t)(a0+r)*UNITS + (kt*32 - GCOLS) + k0];
      *(f16x8*)&As[r][k0] = *(const f16x8*)src;
    }
    {
      const f16* src = &W3T[(size_t)tid*KTOT + kt*32];
      #pragma unroll
      for (int v=0; v<4; v++)
        *(f16x8*)&Bt[tid][v*8] = *(const f16x8*)&src[v*8];
    }
    __syncthreads();
    f16x8 af0 = *(const f16x8*)&As[lr][lq*8];
    f16x8 af1 = *(const f16x8*)&As[16 + lr][lq*8];
    #pragma unroll
    for (int n=0;n<4;n++) {
      f16x8 bf = *(const f16x8*)&Bt[n*64 + w*16 + lr][lq*8];
      acc[0][n] = __builtin_amdgcn_mfma_f32_16x16x32_f16(af0, bf, acc[0][n], 0, 0, 0);
      acc[1][n] = __builtin_amdgcn_mfma_f32_16x16x32_f16(af1, bf, acc[1][n], 0, 0, 0);
    }
    __syncthreads();
  }

  int i = w*16 + lr;
  float bz  = bias2[i];
  float br  = bias2[64 + i];
  float bh  = bias2[128 + i];
  float brh = bias2[192 + i];
  #pragma unroll
  for (int m=0;m<2;m++) {
    #pragma unroll
    for (int r=0;r<4;r++) {
      int a = a0 + m*16 + lq*4 + r;
      float zs = acc[m][0][r] + bz;
      float rs = acc[m][1][r] + br;
      float xh = acc[m][2][r] + bh;
      float rh = acc[m][3][r] + brh;
      float z  = 1.f/(1.f + __expf(-zs));
      float rr = 1.f/(1.f + __expf(-rs));
      float hh = tanhf(xh + rr*rh);
      float hold = h[(size_t)a*UNITS + i];
      float hn = z*hold + (1.f - z)*hh;
      h[(size_t)a*UNITS + i] = hn;
      h16[(size_t)a*UNITS + i] = (f16)hn;
    }
  }
}

extern "C" void kernel_launch(void* const* d_in, const int* in_sizes, int n_in,
                              void* d_out, int out_size, void* d_ws, size_t ws_size,
                              hipStream_t stream) {
  const float* atom  = (const float*)d_in[0];
  const float* bond  = (const float*)d_in[1];
  const int*   pair  = (const int*)d_in[2];
  const float* ek    = (const float*)d_in[3];
  const float* eb    = (const float*)d_in[4];
  const float* gk    = (const float*)d_in[5];
  const float* grk   = (const float*)d_in[6];
  const float* gbias = (const float*)d_in[7];

  float* h = (float*)d_out;                          // 20000x64 fp32

  char* w = (char*)d_ws;
  int*   row_ptr = (int*)w;        w += (size_t)20004*4;          // 16B-mult
  f16*   h16     = (f16*)w;        w += (size_t)N_ATOMS*UNITS*2;
  f16*   W3T     = (f16*)w;        w += (size_t)NCOLS*KTOT*2;
  float* bias2   = (float*)w;      w += (size_t)256*4;
  f16*   G       = (f16*)w;

  init_h<<<(N_ATOMS*UNITS+255)/256, 256, 0, stream>>>(atom, h, h16);
  build_rowptr<<<(N_EDGES+255)/256, 256, 0, stream>>>(pair, row_ptr);
  build_w3t<<<(NCOLS*KTOT+255)/256, 256, 0, stream>>>(ek, eb, gk, grk, gbias, W3T, bias2);

  for (int s=0; s<STEPS; s++) {
    edge_g<<<(N_ATOMS+3)/4, 256, 0, stream>>>(pair, row_ptr, bond, h16, G);
    gru2<<<N_ATOMS/32, 256, 0, stream>>>(G, h16, W3T, bias2, h);
  }
}

// Round 6
// 313.615 us; speedup vs baseline: 1.8162x; 1.0711x over previous
//
#include <hip/hip_runtime.h>

#define N_ATOMS 20000
#define N_EDGES 80000
#define ATOM_DIM 29
#define BOND_DIM 11
#define UNITS 64
#define STEPS 4
#define GCOLS 768      // 12*64 (11 bond slices + 1 plain-sum slice)
#define KTOT  832      // 768 (G) + 64 (h)
#define NCOLS 256      // 4 comps x 64 units
#define APAD  8        // row stride 840 f16 = 105 dwords*4 -> odd sigma, slot-uniform

typedef _Float16 f16;
typedef __attribute__((ext_vector_type(8))) _Float16 f16x8;
typedef __attribute__((ext_vector_type(4))) float f32x4;

__global__ void init_h(const float* __restrict__ atom, float* __restrict__ h,
                       f16* __restrict__ h16) {
    int idx = blockIdx.x*256 + threadIdx.x;
    if (idx >= N_ATOMS*UNITS) return;
    int a = idx >> 6, i = idx & 63;
    float v = (i < ATOM_DIM) ? atom[a*ATOM_DIM + i] : 0.f;
    h[idx] = v;
    h16[idx] = (f16)v;
}

// row_ptr[a] = first edge index with src >= a (edges sorted by src)
__global__ void build_rowptr(const int* __restrict__ pair, int* __restrict__ row_ptr) {
    int e = blockIdx.x*256 + threadIdx.x;
    if (e >= N_EDGES) return;
    int s = pair[2*e];
    if (e == 0) for (int a = 0; a <= s; a++) row_ptr[a] = 0;
    int snext = (e == N_EDGES-1) ? N_ATOMS : pair[2*(e+1)];
    for (int a = s+1; a <= snext; a++) row_ptr[a] = e+1;
}

// W3T[c][k] (f16, 256 x 832), c = comp*64+i, comp: 0=zsum 1=rsum 2=xh 3=rh.
// k<768 (k=b*64+q): sum_m E[k,m]*W2top[m,c], E[k,m]=ek[b,m*64+q] (b<11) or eb[m*64+q].
// k>=768 (j=k-768): W2bot[j,c] from grk. Also bias2[c] (f32) from gb.
__global__ void build_w3t(const float* __restrict__ ek, const float* __restrict__ eb,
                          const float* __restrict__ gk, const float* __restrict__ grk,
                          const float* __restrict__ gb, f16* __restrict__ W3T,
                          float* __restrict__ bias2) {
    int idx = blockIdx.x*256 + threadIdx.x;
    if (idx >= NCOLS*KTOT) return;
    int c = idx & 255, k = idx >> 8;
    int comp = c >> 6, i = c & 63;
    if (k == 0) {
        float b;
        if (comp == 0)      b = gb[i]       + gb[192 + i];
        else if (comp == 1) b = gb[64 + i]  + gb[192 + 64 + i];
        else if (comp == 2) b = gb[128 + i];
        else                b = gb[192 + 128 + i];
        bias2[c] = b;
    }
    float val = 0.f;
    if (k < GCOLS) {
        if (comp != 3) {
            int b = k >> 6, q = k & 63;
            const float* E = (b < BOND_DIM) ? (ek + (size_t)b*4096 + q) : (eb + q);
            const float* T = gk + comp*64 + i;
            #pragma unroll 8
            for (int m = 0; m < 64; m++) val += E[m*64] * T[m*192];
        }
    } else {
        int j = k - GCOLS;
        if (comp == 0)      val = grk[j*192 + i];
        else if (comp == 1) val = grk[j*192 + 64 + i];
        else if (comp == 3) val = grk[j*192 + 128 + i];
    }
    W3T[(size_t)c*KTOT + k] = (f16)val;
}

// One fused step: per 32-atom block,
//  phase 1: gather edges -> A-tile [G | h] (32 x 832 f16) in LDS (no HBM G!)
//  phase 2: gates = A @ W3T^T (MFMA, B streamed from L2 direct to regs, NO barriers)
//  phase 3: GRU gate epilogue -> h (fp32), h16_out
// h16 double-buffered across steps (gather reads arbitrary rows).
__global__ __launch_bounds__(256) void fused_step(
    const int* __restrict__ pair, const int* __restrict__ row_ptr,
    const float* __restrict__ bond, const f16* __restrict__ h16_in,
    f16* __restrict__ h16_out, const f16* __restrict__ W3T,
    const float* __restrict__ bias2, float* __restrict__ h) {
  __shared__ f16 As[32][KTOT + APAD];   // 32 x 840 f16 = 53.8 KB
  int a0 = blockIdx.x * 32;
  int tid = threadIdx.x;
  int lane = tid & 63, w = tid >> 6;
  int lq = lane >> 4, lr = lane & 15;

  // ---------- phase 1: gather (wave w owns atoms w*8 .. w*8+7; lane = h-col j)
  for (int r = w*8; r < w*8 + 8; r++) {
    int a = a0 + r;
    int start = row_ptr[a], end = row_ptr[a+1];
    float g[BOND_DIM+1];
    #pragma unroll
    for (int b=0;b<=BOND_DIM;b++) g[b] = 0.f;
    int e = start;
    for (; e + 1 < end; e += 2) {
      int d0 = pair[2*e+1], d1 = pair[2*e+3];
      float h0 = (float)h16_in[(size_t)d0*UNITS + lane];
      float h1 = (float)h16_in[(size_t)d1*UNITS + lane];
      g[BOND_DIM] += h0 + h1;
      #pragma unroll
      for (int b=0;b<BOND_DIM;b++)
        g[b] += bond[e*BOND_DIM + b]*h0 + bond[(e+1)*BOND_DIM + b]*h1;
    }
    if (e < end) {
      int d0 = pair[2*e+1];
      float h0 = (float)h16_in[(size_t)d0*UNITS + lane];
      g[BOND_DIM] += h0;
      #pragma unroll
      for (int b=0;b<BOND_DIM;b++) g[b] += bond[e*BOND_DIM + b]*h0;
    }
    #pragma unroll
    for (int b=0;b<=BOND_DIM;b++) As[r][b*64 + lane] = (f16)g[b];
    As[r][GCOLS + lane] = h16_in[(size_t)a*UNITS + lane];
  }
  __syncthreads();

  // ---------- phase 2: MFMA K-loop, zero barriers, B direct from global (L2)
  f32x4 acc[2][4];
  #pragma unroll
  for (int m=0;m<2;m++)
    #pragma unroll
    for (int n=0;n<4;n++) acc[m][n] = (f32x4){0.f,0.f,0.f,0.f};

  const f16* b0p = W3T + (size_t)(0*64 + w*16 + lr)*KTOT + lq*8;
  const f16* b1p = W3T + (size_t)(1*64 + w*16 + lr)*KTOT + lq*8;
  const f16* b2p = W3T + (size_t)(2*64 + w*16 + lr)*KTOT + lq*8;
  const f16* b3p = W3T + (size_t)(3*64 + w*16 + lr)*KTOT + lq*8;

  #pragma unroll 2
  for (int kt = 0; kt < KTOT/32; kt++) {
    f16x8 af0 = *(const f16x8*)&As[lr][kt*32 + lq*8];
    f16x8 af1 = *(const f16x8*)&As[16 + lr][kt*32 + lq*8];
    f16x8 bf0 = *(const f16x8*)&b0p[kt*32];
    f16x8 bf1 = *(const f16x8*)&b1p[kt*32];
    f16x8 bf2 = *(const f16x8*)&b2p[kt*32];
    f16x8 bf3 = *(const f16x8*)&b3p[kt*32];
    acc[0][0] = __builtin_amdgcn_mfma_f32_16x16x32_f16(af0, bf0, acc[0][0], 0, 0, 0);
    acc[1][0] = __builtin_amdgcn_mfma_f32_16x16x32_f16(af1, bf0, acc[1][0], 0, 0, 0);
    acc[0][1] = __builtin_amdgcn_mfma_f32_16x16x32_f16(af0, bf1, acc[0][1], 0, 0, 0);
    acc[1][1] = __builtin_amdgcn_mfma_f32_16x16x32_f16(af1, bf1, acc[1][1], 0, 0, 0);
    acc[0][2] = __builtin_amdgcn_mfma_f32_16x16x32_f16(af0, bf2, acc[0][2], 0, 0, 0);
    acc[1][2] = __builtin_amdgcn_mfma_f32_16x16x32_f16(af1, bf2, acc[1][2], 0, 0, 0);
    acc[0][3] = __builtin_amdgcn_mfma_f32_16x16x32_f16(af0, bf3, acc[0][3], 0, 0, 0);
    acc[1][3] = __builtin_amdgcn_mfma_f32_16x16x32_f16(af1, bf3, acc[1][3], 0, 0, 0);
  }

  // ---------- phase 3: GRU epilogue (lane-local: i = w*16+lr)
  int i = w*16 + lr;
  float bz  = bias2[i];
  float br  = bias2[64 + i];
  float bh  = bias2[128 + i];
  float brh = bias2[192 + i];
  #pragma unroll
  for (int m=0;m<2;m++) {
    #pragma unroll
    for (int r=0;r<4;r++) {
      int a = a0 + m*16 + lq*4 + r;
      float zs = acc[m][0][r] + bz;
      float rs = acc[m][1][r] + br;
      float xh = acc[m][2][r] + bh;
      float rh = acc[m][3][r] + brh;
      float z  = 1.f/(1.f + __expf(-zs));
      float rr = 1.f/(1.f + __expf(-rs));
      float hh = tanhf(xh + rr*rh);
      float hold = h[(size_t)a*UNITS + i];
      float hn = z*hold + (1.f - z)*hh;
      h[(size_t)a*UNITS + i] = hn;
      h16_out[(size_t)a*UNITS + i] = (f16)hn;
    }
  }
}

extern "C" void kernel_launch(void* const* d_in, const int* in_sizes, int n_in,
                              void* d_out, int out_size, void* d_ws, size_t ws_size,
                              hipStream_t stream) {
  const float* atom  = (const float*)d_in[0];
  const float* bond  = (const float*)d_in[1];
  const int*   pair  = (const int*)d_in[2];
  const float* ek    = (const float*)d_in[3];
  const float* eb    = (const float*)d_in[4];
  const float* gk    = (const float*)d_in[5];
  const float* grk   = (const float*)d_in[6];
  const float* gbias = (const float*)d_in[7];

  float* h = (float*)d_out;                          // 20000x64 fp32

  char* w = (char*)d_ws;
  int*   row_ptr = (int*)w;        w += 80032;                    // 20004 ints, 16B-pad
  f16*   h16a    = (f16*)w;        w += (size_t)N_ATOMS*UNITS*2;
  f16*   h16b    = (f16*)w;        w += (size_t)N_ATOMS*UNITS*2;
  f16*   W3T     = (f16*)w;        w += (size_t)NCOLS*KTOT*2;
  float* bias2   = (float*)w;      w += (size_t)256*4;

  init_h<<<(N_ATOMS*UNITS+255)/256, 256, 0, stream>>>(atom, h, h16a);
  build_rowptr<<<(N_EDGES+255)/256, 256, 0, stream>>>(pair, row_ptr);
  build_w3t<<<(NCOLS*KTOT+255)/256, 256, 0, stream>>>(ek, eb, gk, grk, gbias, W3T, bias2);

  f16* bufs[2] = { h16a, h16b };
  for (int s=0; s<STEPS; s++) {
    fused_step<<<N_ATOMS/32, 256, 0, stream>>>(
        pair, row_ptr, bond, bufs[s & 1], bufs[(s+1) & 1], W3T, bias2, h);
  }
}